// Round 7
// baseline (29.267 us; speedup 1.0000x reference)
//
#include <hip/hip_runtime.h>

#define BROWS   8192
#define TPB     256
#define NTILE   (BROWS / TPB)     // 32
#define NBLOCKS (NTILE * NTILE)   // 1024 blocks = 4/CU, 4 waves/SIMD

// loss = (1e-4 + sum_ij |A_i - D_i . logp_j|) / B^2   (C = 2)
// A_i = p.logp - q.log q ; D = p - q ; q = clip(onehot,1e-4,1)*class_w
//
// Single dispatch: blocks write partials to ws, last-to-finish block (ticket
// atomics, base-invariant mod-NBLOCKS test) reduces them and writes out.
// Ticket is restored by atomicSub so ws state is identical before/after
// every call (no cross-call state, deterministic work & output).

__global__ __launch_bounds__(TPB) void fused_pair_loss_kernel(
    const float* __restrict__ s,        // [B,2]
    const float* __restrict__ cw,       // [2]
    const int*   __restrict__ t,        // [B]
    float*    __restrict__ partials,    // [NBLOCKS]   (d_ws)
    unsigned* __restrict__ ticket,      // [1]         (d_ws)
    float*    __restrict__ out)         // [1]
{
    const int tid = threadIdx.x;
    const int bid = blockIdx.x;
    const int bx  = bid & (NTILE - 1);  // i-tile
    const int by  = bid >> 5;           // j-tile
    const float w0 = cw[0], w1 = cw[1];

    // ---- my i-row stats (registers) ----
    const int i = bx * TPB + tid;
    float2 si = *reinterpret_cast<const float2*>(s + 2 * i);
    float mi  = fmaxf(si.x, si.y);
    float ei0 = __expf(si.x - mi), ei1 = __expf(si.y - mi);
    float lsei = mi + __logf(ei0 + ei1);
    float li0 = si.x - lsei, li1 = si.y - lsei;
    float p0  = __expf(li0),  p1  = __expf(li1);
    const int ti = t[i];
    float q0 = (ti == 0 ? 1.0f : 1e-4f) * w0;
    float q1 = (ti == 1 ? 1.0f : 1e-4f) * w1;
    float A  = p0 * li0 + p1 * li1 - q0 * __logf(q0) - q1 * __logf(q1);
    float D0 = p0 - q0, D1 = p1 - q1;

    // ---- 256 j-row logp into LDS, SoA + 16B aligned for b128 broadcasts ----
    __shared__ __align__(16) float ljx[TPB];
    __shared__ __align__(16) float ljy[TPB];
    const int j = by * TPB + tid;
    float2 sj = *reinterpret_cast<const float2*>(s + 2 * j);
    float mj  = fmaxf(sj.x, sj.y);
    float ej0 = __expf(sj.x - mj), ej1 = __expf(sj.y - mj);
    float lsej = mj + __logf(ej0 + ej1);
    ljx[tid] = sj.x - lsej;
    ljy[tid] = sj.y - lsej;
    __syncthreads();

    // ---- 256 pairs/thread; uniform b128 broadcasts; 4 ILP chains ----
    float a0 = 0.0f, a1 = 0.0f, a2 = 0.0f, a3 = 0.0f;
#pragma unroll
    for (int k = 0; k < TPB; k += 4) {
        float4 x = *reinterpret_cast<const float4*>(&ljx[k]);
        float4 y = *reinterpret_cast<const float4*>(&ljy[k]);
        a0 += fabsf(A - D0 * x.x - D1 * y.x);
        a1 += fabsf(A - D0 * x.y - D1 * y.y);
        a2 += fabsf(A - D0 * x.z - D1 * y.z);
        a3 += fabsf(A - D0 * x.w - D1 * y.w);
    }
    float acc = (a0 + a1) + (a2 + a3);

    // ---- block reduce: 64-lane wave shuffles + LDS across 4 waves ----
    for (int off = 32; off > 0; off >>= 1)
        acc += __shfl_down(acc, off, 64);
    __shared__ float wsum[TPB / 64];
    if ((tid & 63) == 0) wsum[tid >> 6] = acc;
    __syncthreads();

    // ---- publish partial, draw ticket; last block reduces ----
    __shared__ int amLast;
    if (tid == 0) {
        partials[bid] = wsum[0] + wsum[1] + wsum[2] + wsum[3];
        __threadfence();                       // device-scope: partial visible
        unsigned old = atomicAdd(ticket, 1u);  // device-scope by default
        amLast = ((old & (NBLOCKS - 1u)) == (NBLOCKS - 1u));
        if (amLast)
            atomicSub(ticket, (unsigned)NBLOCKS);  // restore base: no residue
    }
    __syncthreads();

    if (amLast) {
        // 256 threads x 4 coherent loads = 1024 partials
        float a = 0.0f;
#pragma unroll
        for (int r = 0; r < NBLOCKS / TPB; ++r)
            a += __hip_atomic_load(&partials[tid + r * TPB],
                                   __ATOMIC_RELAXED, __HIP_MEMORY_SCOPE_AGENT);
        for (int off = 32; off > 0; off >>= 1)
            a += __shfl_down(a, off, 64);
        __shared__ float wsum2[TPB / 64];
        if ((tid & 63) == 0) wsum2[tid >> 6] = a;
        __syncthreads();
        if (tid == 0) {
            const float inv = 1.0f / ((float)BROWS * (float)BROWS);
            out[0] = (1e-4f + wsum2[0] + wsum2[1] + wsum2[2] + wsum2[3]) * inv;
        }
    }
}

extern "C" void kernel_launch(void* const* d_in, const int* in_sizes, int n_in,
                              void* d_out, int out_size, void* d_ws, size_t ws_size,
                              hipStream_t stream) {
    const float* s  = (const float*)d_in[0];
    const float* cw = (const float*)d_in[1];
    const int*   t  = (const int*)d_in[2];
    float* out      = (float*)d_out;
    float*    partials = (float*)d_ws;                       // 1024 floats
    unsigned* ticket   = (unsigned*)((char*)d_ws + 4096);    // 1 uint, ends each call at its base value

    fused_pair_loss_kernel<<<NBLOCKS, TPB, 0, stream>>>(s, cw, t,
                                                        partials, ticket, out);
}

// Round 8
// 13.008 us; speedup vs baseline: 2.2500x; 2.2500x over previous
//
#include <hip/hip_runtime.h>

#define BROWS   8192
#define TPB     256
#define NTILE   (BROWS / TPB)     // 32 -> grid 32x32 = 1024 blocks (4/CU, 4 waves/SIMD)
#define NBLOCKS (NTILE * NTILE)

// loss = (1e-4 + sum_ij |A_i - D_i . logp_j|) / B^2   (C = 2)
// A_i = p.logp - q.log q ; D = p - q ; q = clip(onehot,1e-4,1)*class_w
//
// Structure notes (measured, MI355X):
//  - 2 dispatches (partials + tiny reduce) is optimal. All single-dispatch
//    variants lose big: grid.sync +47us, same-address atomic burst +15us,
//    threadfence+ticket +16us (device-scope coherence across 8 XCDs).
//  - 1024 blocks = 4/CU = 4 waves/SIMD: needed for issue-bound TLP (256-block
//    variant regressed 2.4us).
//  - Inner-loop VALU count is NOT the wall (pk_fma was neutral): exec ~4.5us,
//    ~8.5us is fixed 2-node graph launch overhead.

__global__ __launch_bounds__(TPB) void pair_partial_kernel(
    const float* __restrict__ s,        // [B,2]
    const float* __restrict__ cw,       // [2]
    const int*   __restrict__ t,        // [B]
    float* __restrict__ partials)       // [NBLOCKS]
{
    const int tid = threadIdx.x;
    const int bx  = blockIdx.x;         // i-tile
    const int by  = blockIdx.y;         // j-tile
    const float w0 = cw[0], w1 = cw[1];

    // ---- my i-row stats (registers) ----
    const int i = bx * TPB + tid;
    float2 si = *reinterpret_cast<const float2*>(s + 2 * i);
    float mi  = fmaxf(si.x, si.y);
    float ei0 = __expf(si.x - mi), ei1 = __expf(si.y - mi);
    float lsei = mi + __logf(ei0 + ei1);
    float li0 = si.x - lsei, li1 = si.y - lsei;
    float p0  = __expf(li0),  p1  = __expf(li1);
    const int ti = t[i];
    float q0 = (ti == 0 ? 1.0f : 1e-4f) * w0;
    float q1 = (ti == 1 ? 1.0f : 1e-4f) * w1;
    float A  = p0 * li0 + p1 * li1 - q0 * __logf(q0) - q1 * __logf(q1);
    float D0 = p0 - q0, D1 = p1 - q1;

    // ---- 256 j-row logp into LDS, SoA + 16B aligned for b128 broadcasts ----
    __shared__ __align__(16) float ljx[TPB];
    __shared__ __align__(16) float ljy[TPB];
    const int j = by * TPB + tid;
    float2 sj = *reinterpret_cast<const float2*>(s + 2 * j);
    float mj  = fmaxf(sj.x, sj.y);
    float ej0 = __expf(sj.x - mj), ej1 = __expf(sj.y - mj);
    float lsej = mj + __logf(ej0 + ej1);
    ljx[tid] = sj.x - lsej;
    ljy[tid] = sj.y - lsej;
    __syncthreads();

    // ---- 256 pairs/thread; uniform b128 broadcasts (0 conflicts); 4 ILP chains
    float a0 = 0.0f, a1 = 0.0f, a2 = 0.0f, a3 = 0.0f;
#pragma unroll
    for (int k = 0; k < TPB; k += 4) {
        float4 x = *reinterpret_cast<const float4*>(&ljx[k]);
        float4 y = *reinterpret_cast<const float4*>(&ljy[k]);
        a0 += fabsf(A - D0 * x.x - D1 * y.x);
        a1 += fabsf(A - D0 * x.y - D1 * y.y);
        a2 += fabsf(A - D0 * x.z - D1 * y.z);
        a3 += fabsf(A - D0 * x.w - D1 * y.w);
    }
    float acc = (a0 + a1) + (a2 + a3);

    // ---- block reduce: 64-lane wave shuffles + LDS across 4 waves ----
    for (int off = 32; off > 0; off >>= 1)
        acc += __shfl_down(acc, off, 64);
    __shared__ float wsum[TPB / 64];
    if ((tid & 63) == 0) wsum[tid >> 6] = acc;
    __syncthreads();
    if (tid == 0)
        partials[by * NTILE + bx] = wsum[0] + wsum[1] + wsum[2] + wsum[3];
}

// single-wave final reduce: 64 lanes x 4 float4 = 1024 partials
__global__ __launch_bounds__(64) void final_reduce_kernel(
    const float* __restrict__ partials, float* __restrict__ out)
{
    const int lane = threadIdx.x;
    const float4* p4 = reinterpret_cast<const float4*>(partials);
    float a = 0.0f;
#pragma unroll
    for (int r = 0; r < NBLOCKS / 256; ++r) {
        float4 v = p4[lane + r * 64];
        a += (v.x + v.y) + (v.z + v.w);
    }
    for (int off = 32; off > 0; off >>= 1)
        a += __shfl_down(a, off, 64);
    if (lane == 0) {
        const float inv = 1.0f / ((float)BROWS * (float)BROWS);
        out[0] = (1e-4f + a) * inv;
    }
}

extern "C" void kernel_launch(void* const* d_in, const int* in_sizes, int n_in,
                              void* d_out, int out_size, void* d_ws, size_t ws_size,
                              hipStream_t stream) {
    const float* s  = (const float*)d_in[0];
    const float* cw = (const float*)d_in[1];
    const int*   t  = (const int*)d_in[2];
    float* out      = (float*)d_out;
    float* partials = (float*)d_ws;   // NBLOCKS floats, fully overwritten each call

    dim3 grid(NTILE, NTILE);          // 1024 blocks of 256x256 pairs
    pair_partial_kernel<<<grid, TPB, 0, stream>>>(s, cw, t, partials);
    final_reduce_kernel<<<1, 64, 0, stream>>>(partials, out);
}